// Round 1
// baseline (111.207 us; speedup 1.0000x reference)
//
#include <hip/hip_runtime.h>
#include <math.h>

#define BB 64
#define CC 32
#define DD 256
#define TEMP 0.1f
#define EPSC 1e-8f

__device__ __forceinline__ float wave_reduce_sum(float v) {
    #pragma unroll
    for (int off = 32; off > 0; off >>= 1)
        v += __shfl_down(v, off, 64);
    return v;
}

// Kernel 1: per-row squared norms, anchor norms, positive similarity.
// grid = B, block = 256 (4 waves). Wave w handles rows c = w*8 .. w*8+7.
// Each row is 256 floats = 64 lanes x float4.
__global__ void norms_pos_kernel(const float* __restrict__ xis,
                                 const float* __restrict__ xjs,
                                 float* __restrict__ rn_i,   // [B*C] row sumsq of is
                                 float* __restrict__ rn_j,   // [B*C] row sumsq of js
                                 float* __restrict__ norm_i, // [B]
                                 float* __restrict__ norm_j, // [B]
                                 float* __restrict__ pos)    // [B]
{
    const int b = blockIdx.x;
    const int wave = threadIdx.x >> 6;
    const int lane = threadIdx.x & 63;
    __shared__ float s_ii[4], s_jj[4], s_ij[4];

    float ii_acc = 0.f, jj_acc = 0.f, ij_acc = 0.f;
    #pragma unroll
    for (int r0 = 0; r0 < 8; ++r0) {
        const int r = wave * 8 + r0;
        const float4* ap = (const float4*)(xis + ((size_t)b * CC + r) * DD);
        const float4* bp = (const float4*)(xjs + ((size_t)b * CC + r) * DD);
        float4 a = ap[lane];
        float4 bv = bp[lane];
        float sii = a.x*a.x + a.y*a.y + a.z*a.z + a.w*a.w;
        float sjj = bv.x*bv.x + bv.y*bv.y + bv.z*bv.z + bv.w*bv.w;
        float sij = a.x*bv.x + a.y*bv.y + a.z*bv.z + a.w*bv.w;
        sii = wave_reduce_sum(sii);
        sjj = wave_reduce_sum(sjj);
        sij = wave_reduce_sum(sij);
        if (lane == 0) {
            rn_i[b * CC + r] = sii;
            rn_j[b * CC + r] = sjj;
            ii_acc += sii; jj_acc += sjj; ij_acc += sij;
        }
    }
    if (lane == 0) { s_ii[wave] = ii_acc; s_jj[wave] = jj_acc; s_ij[wave] = ij_acc; }
    __syncthreads();
    if (threadIdx.x == 0) {
        float ii = 0.f, jj = 0.f, ij = 0.f;
        #pragma unroll
        for (int w = 0; w < 4; ++w) { ii += s_ii[w]; jj += s_jj[w]; ij += s_ij[w]; }
        float ni = sqrtf(ii), nj = sqrtf(jj);
        norm_i[b] = ni;
        norm_j[b] = nj;
        pos[b] = ij / fmaxf(ni * nj, EPSC) / TEMP;
    }
}

// Kernel 2: sim_j[i,m], sim_k[i,m] for all pairs.
// grid = (B, B): blockIdx.x = m, blockIdx.y = i. block = 256 (4 waves).
// Wave w handles c = w*8 .. w*8+7; each gathered row dot is 64 lanes x float4.
__global__ void sim_kernel(const float* __restrict__ xis,
                           const float* __restrict__ xjs,
                           const int* __restrict__ idxj,
                           const int* __restrict__ idxk,
                           const float* __restrict__ rn_i,
                           const float* __restrict__ rn_j,
                           const float* __restrict__ norm_i,
                           float* __restrict__ sim_j,  // [B*B]
                           float* __restrict__ sim_k)  // [B*B]
{
    const int m = blockIdx.x;
    const int i = blockIdx.y;
    const int wave = threadIdx.x >> 6;
    const int lane = threadIdx.x & 63;
    __shared__ float s[4][4];

    float dj = 0.f, dk = 0.f, n2j = 0.f, n2k = 0.f;
    const size_t pair_base = ((size_t)i * BB + m) * CC;
    #pragma unroll
    for (int c0 = 0; c0 < 8; ++c0) {
        const int c = wave * 8 + c0;
        const int ij = idxj[pair_base + c];
        const int ik = idxk[pair_base + c];
        const float4* ap = (const float4*)(xis + ((size_t)i * CC + c) * DD);
        const float4* jp = (const float4*)(xjs + ((size_t)m * CC + ij) * DD);
        const float4* kp = (const float4*)(xis + ((size_t)m * CC + ik) * DD);
        float4 a = ap[lane];
        float4 jv = jp[lane];
        float4 kv = kp[lane];
        dj += a.x*jv.x + a.y*jv.y + a.z*jv.z + a.w*jv.w;
        dk += a.x*kv.x + a.y*kv.y + a.z*kv.z + a.w*kv.w;
        if (lane == 0) {
            n2j += rn_j[m * CC + ij];
            n2k += rn_i[m * CC + ik];
        }
    }
    dj = wave_reduce_sum(dj);
    dk = wave_reduce_sum(dk);
    if (lane == 0) { s[wave][0] = dj; s[wave][1] = dk; s[wave][2] = n2j; s[wave][3] = n2k; }
    __syncthreads();
    if (threadIdx.x == 0) {
        float DJ = 0.f, DK = 0.f, NJ = 0.f, NK = 0.f;
        #pragma unroll
        for (int w = 0; w < 4; ++w) { DJ += s[w][0]; DK += s[w][1]; NJ += s[w][2]; NK += s[w][3]; }
        float oj, ok;
        if (i == m) {
            oj = -INFINITY; ok = -INFINITY;
        } else {
            const float ni = norm_i[i];
            oj = DJ / fmaxf(ni * sqrtf(NJ), EPSC) / TEMP;
            ok = DK / fmaxf(ni * sqrtf(NK), EPSC) / TEMP;
        }
        sim_j[i * BB + m] = oj;
        sim_k[i * BB + m] = ok;
    }
}

// Kernel 3: per-row logsumexp over [pos_i, sim_j[i,:], sim_k[i,:]] (129 logits),
// loss = sum_i(lse_i - pos_i) / (2B). 1 block x 64 threads, lane i = row i.
__global__ void loss_kernel(const float* __restrict__ pos,
                            const float* __restrict__ sim_j,
                            const float* __restrict__ sim_k,
                            float* __restrict__ out)
{
    const int i = threadIdx.x;  // 0..63
    const float p = pos[i];
    float mx = p;
    #pragma unroll 4
    for (int m = 0; m < BB; ++m) mx = fmaxf(mx, sim_j[i * BB + m]);
    #pragma unroll 4
    for (int m = 0; m < BB; ++m) mx = fmaxf(mx, sim_k[i * BB + m]);
    float s = expf(p - mx);
    #pragma unroll 4
    for (int m = 0; m < BB; ++m) s += expf(sim_j[i * BB + m] - mx);  // exp(-inf)=0 on diag
    #pragma unroll 4
    for (int m = 0; m < BB; ++m) s += expf(sim_k[i * BB + m] - mx);
    const float lse = mx + logf(s);
    float v = lse - p;
    v = wave_reduce_sum(v);
    if (i == 0) out[0] = v / (2.0f * BB);
}

extern "C" void kernel_launch(void* const* d_in, const int* in_sizes, int n_in,
                              void* d_out, int out_size, void* d_ws, size_t ws_size,
                              hipStream_t stream) {
    const float* xis  = (const float*)d_in[0];  // children_is [B,C,D] f32
    const float* xjs  = (const float*)d_in[1];  // children_js [B,C,D] f32
    const int*   idxj = (const int*)d_in[2];    // neg_idx_j [B,B,C] i32
    const int*   idxk = (const int*)d_in[3];    // neg_idx_k [B,B,C] i32
    // d_in[4] = partnet_ids (unused by the computation)
    float* out = (float*)d_out;

    // Workspace layout (floats); everything written before read each launch.
    float* ws     = (float*)d_ws;
    float* rn_i   = ws;                 // B*C = 2048
    float* rn_j   = rn_i + BB * CC;     // 2048
    float* norm_i = rn_j + BB * CC;     // 64
    float* norm_j = norm_i + BB;        // 64
    float* pos    = norm_j + BB;        // 64
    float* sim_j  = pos + BB;           // 4096
    float* sim_k  = sim_j + BB * BB;    // 4096

    norms_pos_kernel<<<BB, 256, 0, stream>>>(xis, xjs, rn_i, rn_j, norm_i, norm_j, pos);
    sim_kernel<<<dim3(BB, BB), 256, 0, stream>>>(xis, xjs, idxj, idxk,
                                                 rn_i, rn_j, norm_i, sim_j, sim_k);
    loss_kernel<<<1, 64, 0, stream>>>(pos, sim_j, sim_k, out);
}

// Round 2
// 86.442 us; speedup vs baseline: 1.2865x; 1.2865x over previous
//
#include <hip/hip_runtime.h>
#include <math.h>

#define BB 64
#define CC 32
#define DD 256
#define TEMP 0.1f
#define EPSC 1e-8f

__device__ __forceinline__ float wave_reduce_sum(float v) {
    #pragma unroll
    for (int off = 32; off > 0; off >>= 1)
        v += __shfl_down(v, off, 64);
    return v;
}

// Fused kernel: per-pair similarities + positive + anchor/gathered norms.
// grid = (m=64, chunk=4), block = 256 (4 waves). Each block:
//   - stages js[m] and is[m] (32 KB each) into LDS (gathered-row source)
//   - each wave owns 4 anchors i = chunk*16 + wave*4 + {0..3}; for each i it
//     streams the 32 anchor rows is[i,c] (coalesced float4) and dots them
//     against LDS rows js[m, idxj[i,m,c]] and is[m, idxk[i,m,c]], while
//     accumulating sumsq of anchor and gathered rows in the same pass.
//   - diagonal (i==m): idx := c gives dot(flat_i, flat_j_i) -> pos[i];
//     sim entries set to -inf.
// One __syncthreads total; no cross-wave reduction (wave owns whole anchor).
// sim outputs stored TRANSPOSED: simT[m*BB + i] so the loss kernel reads
// coalesced.
__global__ __launch_bounds__(256) void sim_fused_kernel(
        const float* __restrict__ xis,
        const float* __restrict__ xjs,
        const int* __restrict__ idxj,
        const int* __restrict__ idxk,
        float* __restrict__ pos,     // [B]
        float* __restrict__ sim_jT,  // [B*B], [m][i]
        float* __restrict__ sim_kT)  // [B*B], [m][i]
{
    __shared__ float sj[CC * DD];  // js[m] rows   (32 KB)
    __shared__ float sk[CC * DD];  // is[m] rows   (32 KB)

    const int m = blockIdx.x;
    const int lane = threadIdx.x & 63;
    const int wave = __builtin_amdgcn_readfirstlane(threadIdx.x >> 6);

    // ---- stage js[m], is[m] into LDS (coalesced float4) ----
    {
        const float4* gj4 = (const float4*)(xjs + (size_t)m * CC * DD);
        const float4* gi4 = (const float4*)(xis + (size_t)m * CC * DD);
        float4* sj4 = (float4*)sj;
        float4* sk4 = (float4*)sk;
        #pragma unroll
        for (int k = 0; k < 8; ++k) {           // 2048 float4 per array
            sj4[threadIdx.x + k * 256] = gj4[threadIdx.x + k * 256];
            sk4[threadIdx.x + k * 256] = gi4[threadIdx.x + k * 256];
        }
    }
    __syncthreads();

    const int ibase = blockIdx.y * 16 + wave * 4;

    #pragma unroll
    for (int ii = 0; ii < 4; ++ii) {
        const int i = ibase + ii;
        const bool diag = (i == m);
        const int* __restrict__ pj = idxj + ((size_t)i * BB + m) * CC;
        const int* __restrict__ pk = idxk + ((size_t)i * BB + m) * CC;
        const float4* a4 = (const float4*)(xis + (size_t)i * CC * DD);

        float dj = 0.f, dk = 0.f, naa = 0.f, njj = 0.f, nkk = 0.f;
        #pragma unroll 8
        for (int c = 0; c < CC; ++c) {
            const int ij = diag ? c : pj[c];
            const int ik = diag ? c : pk[c];
            float4 a  = a4[c * (DD / 4) + lane];
            float4 jv = ((const float4*)(sj + ij * DD))[lane];
            float4 kv = ((const float4*)(sk + ik * DD))[lane];
            dj  += a.x * jv.x + a.y * jv.y + a.z * jv.z + a.w * jv.w;
            dk  += a.x * kv.x + a.y * kv.y + a.z * kv.z + a.w * kv.w;
            naa += a.x * a.x  + a.y * a.y  + a.z * a.z  + a.w * a.w;
            njj += jv.x * jv.x + jv.y * jv.y + jv.z * jv.z + jv.w * jv.w;
            nkk += kv.x * kv.x + kv.y * kv.y + kv.z * kv.z + kv.w * kv.w;
        }
        dj  = wave_reduce_sum(dj);
        dk  = wave_reduce_sum(dk);
        naa = wave_reduce_sum(naa);
        njj = wave_reduce_sum(njj);
        nkk = wave_reduce_sum(nkk);

        if (lane == 0) {
            const float ni = sqrtf(naa);
            if (diag) {
                pos[i] = dj / fmaxf(ni * sqrtf(njj), EPSC) / TEMP;
                sim_jT[m * BB + i] = -INFINITY;
                sim_kT[m * BB + i] = -INFINITY;
            } else {
                sim_jT[m * BB + i] = dj / fmaxf(ni * sqrtf(njj), EPSC) / TEMP;
                sim_kT[m * BB + i] = dk / fmaxf(ni * sqrtf(nkk), EPSC) / TEMP;
            }
        }
    }
}

// Loss: per-row fixed-shift logsumexp over [pos_i, sim_j[i,:], sim_k[i,:]].
// Logits are cos/0.1 in [-10, 10], so shift M=10 is exact (lse is
// shift-invariant; exp(x-10) in [e^-20, 1], no over/underflow).
// 1 block x 256 threads: thread (q,i) with q=t>>6 handles m = q*16..q*16+15;
// reads of simT[m*64 + i] are coalesced across lanes.
__global__ __launch_bounds__(256) void loss_kernel(
        const float* __restrict__ pos,
        const float* __restrict__ sim_jT,
        const float* __restrict__ sim_kT,
        float* __restrict__ out)
{
    __shared__ float sp[4][BB];
    const int t = threadIdx.x;
    const int i = t & 63;
    const int q = t >> 6;

    float s = 0.f;
    #pragma unroll 4
    for (int mm = 0; mm < 16; ++mm) {
        const int m = q * 16 + mm;
        s += expf(sim_jT[m * BB + i] - 10.0f);   // exp(-inf)=0 on diagonal
        s += expf(sim_kT[m * BB + i] - 10.0f);
    }
    sp[q][i] = s;
    __syncthreads();

    if (t < 64) {
        const float p = pos[i];
        float tot = sp[0][i] + sp[1][i] + sp[2][i] + sp[3][i] + expf(p - 10.0f);
        float v = 10.0f + logf(tot) - p;
        v = wave_reduce_sum(v);
        if (i == 0) out[0] = v * (1.0f / (2.0f * BB));
    }
}

extern "C" void kernel_launch(void* const* d_in, const int* in_sizes, int n_in,
                              void* d_out, int out_size, void* d_ws, size_t ws_size,
                              hipStream_t stream) {
    const float* xis  = (const float*)d_in[0];  // children_is [B,C,D] f32
    const float* xjs  = (const float*)d_in[1];  // children_js [B,C,D] f32
    const int*   idxj = (const int*)d_in[2];    // neg_idx_j [B,B,C] i32
    const int*   idxk = (const int*)d_in[3];    // neg_idx_k [B,B,C] i32
    // d_in[4] = partnet_ids (unused; reference masks via eye())
    float* out = (float*)d_out;

    float* ws     = (float*)d_ws;
    float* pos    = ws;                 // 64
    float* sim_jT = pos + BB;           // 4096
    float* sim_kT = sim_jT + BB * BB;   // 4096

    sim_fused_kernel<<<dim3(BB, 4), 256, 0, stream>>>(xis, xjs, idxj, idxk,
                                                      pos, sim_jT, sim_kT);
    loss_kernel<<<1, 256, 0, stream>>>(pos, sim_jT, sim_kT, out);
}

// Round 3
// 77.602 us; speedup vs baseline: 1.4330x; 1.1139x over previous
//
#include <hip/hip_runtime.h>
#include <math.h>

#define BB 64
#define CC 32
#define DD 256
#define TEMP 0.1f
#define EPSC 1e-8f

typedef const __attribute__((address_space(1))) unsigned int* gptr_u32;
typedef __attribute__((address_space(3))) unsigned int* lptr_u32;

__device__ __forceinline__ float wave_reduce_sum(float v) {
    #pragma unroll
    for (int off = 32; off > 0; off >>= 1)
        v += __shfl_down(v, off, 64);
    return v;
}

// Fused sim+exp kernel.
// grid = (m=64, chunk=8), block = 256 (4 waves); 512 blocks = 2/CU (64 KB LDS).
// Each block stages js[m], is[m] (32 KB each) into LDS via global_load_lds,
// then each wave owns 2 anchors i = chunk*8 + wave*2 + {0,1}:
//   stream anchor rows is[i,c] (coalesced float4 from L2) and dot against LDS
//   rows js[m,idxj[i,m,c]] / is[m,idxk[i,m,c]], accumulating anchor & gathered
//   sumsq in the same pass. Lane 0 converts to exp((cos/T) - 10) and writes
//   part[m][i] (diag -> 0, pos[i] written instead). Every (m,i) slot is
//   written exactly once across the grid -> no init / atomics needed.
__global__ __launch_bounds__(256) void sim_part_kernel(
        const float* __restrict__ xis,
        const float* __restrict__ xjs,
        const int* __restrict__ idxj,
        const int* __restrict__ idxk,
        float* __restrict__ pos,    // [B]
        float* __restrict__ part)   // [B*B], [m][i]
{
    __shared__ float sj[CC * DD];  // js[m]  (32 KB)
    __shared__ float sk[CC * DD];  // is[m]  (32 KB)

    const int m = blockIdx.x;
    const int lane = threadIdx.x & 63;
    const int wave = __builtin_amdgcn_readfirstlane(threadIdx.x >> 6);

    // ---- stage js[m], is[m] into LDS ----
    {
        const float* gj = xjs + (size_t)m * CC * DD;
        const float* gi = xis + (size_t)m * CC * DD;
#if defined(__has_builtin) && __has_builtin(__builtin_amdgcn_global_load_lds)
        #pragma unroll
        for (int k = 0; k < 8; ++k) {
            const int off = (threadIdx.x + k * 256) * 4;   // float index, 16B/lane
            __builtin_amdgcn_global_load_lds((gptr_u32)(gj + off), (lptr_u32)(sj + off), 16, 0, 0);
            __builtin_amdgcn_global_load_lds((gptr_u32)(gi + off), (lptr_u32)(sk + off), 16, 0, 0);
        }
#else
        const float4* gj4 = (const float4*)gj;
        const float4* gi4 = (const float4*)gi;
        float4* sj4 = (float4*)sj;
        float4* sk4 = (float4*)sk;
        #pragma unroll
        for (int k = 0; k < 8; ++k) {
            sj4[threadIdx.x + k * 256] = gj4[threadIdx.x + k * 256];
            sk4[threadIdx.x + k * 256] = gi4[threadIdx.x + k * 256];
        }
#endif
    }
    __syncthreads();   // drains vmcnt (incl. global_load_lds) before LDS reads

    const int ibase = blockIdx.y * 8 + wave * 2;

    #pragma unroll
    for (int ii = 0; ii < 2; ++ii) {
        const int i = ibase + ii;
        const bool diag = (i == m);
        const int* __restrict__ pj = idxj + ((size_t)i * BB + m) * CC;  // wave-uniform -> s_load
        const int* __restrict__ pk = idxk + ((size_t)i * BB + m) * CC;
        const float4* a4 = (const float4*)(xis + (size_t)i * CC * DD);

        float dj = 0.f, dk = 0.f, naa = 0.f, njj = 0.f, nkk = 0.f;
        #pragma unroll 8
        for (int c = 0; c < CC; ++c) {
            const int ij = diag ? c : pj[c];
            const int ik = diag ? c : pk[c];
            float4 a  = a4[c * (DD / 4) + lane];
            float4 jv = ((const float4*)(sj + ij * DD))[lane];
            float4 kv = ((const float4*)(sk + ik * DD))[lane];
            dj  += a.x * jv.x + a.y * jv.y + a.z * jv.z + a.w * jv.w;
            dk  += a.x * kv.x + a.y * kv.y + a.z * kv.z + a.w * kv.w;
            naa += a.x * a.x  + a.y * a.y  + a.z * a.z  + a.w * a.w;
            njj += jv.x * jv.x + jv.y * jv.y + jv.z * jv.z + jv.w * jv.w;
            nkk += kv.x * kv.x + kv.y * kv.y + kv.z * kv.z + kv.w * kv.w;
        }
        dj  = wave_reduce_sum(dj);
        dk  = wave_reduce_sum(dk);
        naa = wave_reduce_sum(naa);
        njj = wave_reduce_sum(njj);
        nkk = wave_reduce_sum(nkk);

        if (lane == 0) {
            const float ni = sqrtf(naa);
            if (diag) {
                pos[i] = dj / fmaxf(ni * sqrtf(njj), EPSC) / TEMP;
                part[m * BB + i] = 0.0f;
            } else {
                const float s1 = dj / fmaxf(ni * sqrtf(njj), EPSC) / TEMP;
                const float s2 = dk / fmaxf(ni * sqrtf(nkk), EPSC) / TEMP;
                // logits are cos/0.1 in [-10,10]: fixed shift 10 is exact
                part[m * BB + i] = expf(s1 - 10.0f) + expf(s2 - 10.0f);
            }
        }
    }
}

// Loss: lse_i = 10 + log(sum_m part[m][i] + exp(pos_i - 10));
// loss = sum_i (lse_i - pos_i) / (2B). 1 block x 256 threads; thread (q,i)
// sums m = q*16..q*16+15 (reads part[m*64+i]: lane-contiguous, coalesced).
__global__ __launch_bounds__(256) void loss_kernel(
        const float* __restrict__ pos,
        const float* __restrict__ part,
        float* __restrict__ out)
{
    __shared__ float sp[4][BB];
    const int t = threadIdx.x;
    const int i = t & 63;
    const int q = t >> 6;

    float s = 0.f;
    #pragma unroll
    for (int mm = 0; mm < 16; ++mm)
        s += part[(q * 16 + mm) * BB + i];
    sp[q][i] = s;
    __syncthreads();

    if (t < 64) {
        const float p = pos[i];
        const float tot = sp[0][i] + sp[1][i] + sp[2][i] + sp[3][i] + expf(p - 10.0f);
        float v = 10.0f + logf(tot) - p;
        v = wave_reduce_sum(v);
        if (i == 0) out[0] = v * (1.0f / (2.0f * BB));
    }
}

extern "C" void kernel_launch(void* const* d_in, const int* in_sizes, int n_in,
                              void* d_out, int out_size, void* d_ws, size_t ws_size,
                              hipStream_t stream) {
    const float* xis  = (const float*)d_in[0];  // children_is [B,C,D] f32
    const float* xjs  = (const float*)d_in[1];  // children_js [B,C,D] f32
    const int*   idxj = (const int*)d_in[2];    // neg_idx_j [B,B,C] i32
    const int*   idxk = (const int*)d_in[3];    // neg_idx_k [B,B,C] i32
    // d_in[4] = partnet_ids (unused; reference masks via eye())
    float* out = (float*)d_out;

    float* ws   = (float*)d_ws;
    float* pos  = ws;               // 64 floats
    float* part = pos + BB;         // 4096 floats, [m][i]

    sim_part_kernel<<<dim3(BB, 8), 256, 0, stream>>>(xis, xjs, idxj, idxk, pos, part);
    loss_kernel<<<1, 256, 0, stream>>>(pos, part, out);
}